// Round 11
// baseline (78.615 us; speedup 1.0000x reference)
//
#include <hip/hip_runtime.h>
#include <math.h>

// KShape dists via bf16 MFMA. B=256, K=16, SZ=512, D=8.
// corr[b,i,k] = sum_{t,d} xpad[b][(i+t)*8+d] * c[k][t*8+d],  i in [0,1022]
// dists[b,k] = max_i corr / (||x_b|| * k); k=0 -> 0. labels = first argmax.
// out: [0..255]=labels(float), [256..4351]=dists.
//
// R11: dual-pipe operand streaming. Prep kernel writes a zero-padded bf16
// A-image xpad[b][1120][8] (one 16B row = one A-fragment line) + norms to
// d_ws. Main kernel (256 blocks x 1024 thr, 1/CU, 4 waves/SIMD, <=128 reg):
// B = whole packed centers in LDS (132 kc rows incl. 4-row lookahead pad,
// no wrap VALU); A-ring refills = global_load_dwordx4 from xpad (24 KB/block
// -> L1-resident, vector-memory pipe). Per iter: 1 ds_read_b128 + 1 global
// dwordx4 + 4 MFMA -- LDS instruction load halved vs R10, A on parallel pipe.
// Same trapezoid windows, same arithmetic order as R8/R10 (absmax 0.015625).

#define NB 256
#define NK 16
#define NS 512
#define ND 8
#define XROWS 1120   // max row touched = 64*15 + 4*(khi+16) + 19 = 1103

typedef __bf16 bf16x8 __attribute__((ext_vector_type(8)));
typedef float floatx4 __attribute__((ext_vector_type(4)));

#define MFMA(q, bv, a) __builtin_amdgcn_mfma_f32_16x16x32_bf16(q, bv, a, 0, 0, 0)

// ---- prep: build bf16 padded A-image + norms ----
__global__ __launch_bounds__(256) void prep_kernel(
    const float* __restrict__ x, __bf16* __restrict__ xpad, float* __restrict__ wsfn)
{
    __shared__ float redn[4];
    const int tid = threadIdx.x;
    const int b   = blockIdx.x;
    __bf16* dst = xpad + (size_t)b * XROWS * 8;

    float ss = 0.f;
    for (int jj = tid; jj < XROWS; jj += 256) {
        bf16x8 v;
        if (jj >= 511 && jj < 1023) {
            const float4* p = (const float4*)(x + ((size_t)b * NS + (size_t)(jj - 511)) * ND);
            float4 a = p[0], bb = p[1];
            ss += a.x * a.x + a.y * a.y + a.z * a.z + a.w * a.w;
            ss += bb.x * bb.x + bb.y * bb.y + bb.z * bb.z + bb.w * bb.w;
            v[0] = (__bf16)a.x;  v[1] = (__bf16)a.y;  v[2] = (__bf16)a.z;  v[3] = (__bf16)a.w;
            v[4] = (__bf16)bb.x; v[5] = (__bf16)bb.y; v[6] = (__bf16)bb.z; v[7] = (__bf16)bb.w;
        } else {
            #pragma unroll
            for (int e = 0; e < 8; ++e) v[e] = (__bf16)0.0f;
        }
        *(bf16x8*)(dst + (size_t)jj * 8) = v;
    }
    #pragma unroll
    for (int off = 32; off; off >>= 1) ss += __shfl_down(ss, off);
    if ((tid & 63) == 0) redn[tid >> 6] = ss;
    __syncthreads();
    if (tid == 0) wsfn[b] = sqrtf(redn[0] + redn[1] + redn[2] + redn[3]);
}

// ---- main: one block = one b; 16 waves x 4 row-tiles = 1024 lag rows ----
__global__ __launch_bounds__(1024, 4) void kshape_kernel(
    const __bf16* __restrict__ xpad, const float* __restrict__ c,
    const float* __restrict__ wsfn, float* __restrict__ out)
{
    __shared__ __align__(16) __bf16 Bf[132 * 512];   // 132 KB: packed B + 4-kc pad
    __shared__ float wred[16][16];
    __shared__ float dd[16];

    const int tid = threadIdx.x;
    const int b   = blockIdx.x;

    // ---- pack ALL of B into LDS directly from c (fragment order) ----
    // Bf[kc*512 + L*8 + j] = bf16( c[n=L&15][(kc*4 + (L>>4))*8 + j] )
    #pragma unroll 4
    for (int i = 0; i < 8; ++i) {
        int idx = tid + i * 1024;          // fragment id 0..8191 (kc = idx>>6)
        int kc = idx >> 6, Lf = idx & 63;
        int n = Lf & 15, qd = Lf >> 4;
        const float4* src = (const float4*)(c + ((size_t)n * NS + (size_t)(kc * 4 + qd)) * ND);
        float4 a = src[0], bb = src[1];
        bf16x8 v;
        v[0] = (__bf16)a.x;  v[1] = (__bf16)a.y;  v[2] = (__bf16)a.z;  v[3] = (__bf16)a.w;
        v[4] = (__bf16)bb.x; v[5] = (__bf16)bb.y; v[6] = (__bf16)bb.z; v[7] = (__bf16)bb.w;
        *(bf16x8*)(Bf + (size_t)idx * 8) = v;
    }
    // zero the 4-kc lookahead pad (rows 128..131 = 2048 bf16x8... 256 frags)
    if (tid < 256) {
        bf16x8 z;
        #pragma unroll
        for (int e = 0; e < 8; ++e) z[e] = (__bf16)0.0f;
        *(bf16x8*)(Bf + (size_t)(8192 + tid) * 8) = z;
    }
    __syncthreads();                       // the ONE barrier before compute

    const int L    = tid & 63;
    const int m    = L & 15;       // A row within tile / D col (center id)
    const int quad = L >> 4;
    const int wu   = __builtin_amdgcn_readfirstlane(tid >> 6);  // wave 0..15

    // wave-uniform trapezoid window (multiples of 16)
    const int a0  = 112 - 16 * wu;
    const int klo = (a0 > 0) ? a0 : 0;                 // 112,96,...,16,0,0,...
    const int kh_ = (1022 - 64 * wu) >> 2;
    const int khi = (kh_ > 127) ? 127 : kh_;           // 127 x9, 111, ..., 15

    // A-frag (r,kc): 16B at ga + 32*(kc + 4r) [global, L1-resident]
    const __bf16* ga = xpad + (size_t)b * XROWS * 8 + 8 * (64 * wu + m + quad);
    const __bf16* Bl = Bf + L * 8;

    bf16x8 Q[16];
    #pragma unroll
    for (int i = 0; i < 16; ++i) Q[i] = *(const bf16x8*)(ga + 32 * (klo + i));

    bf16x8 Bv[4];
    #pragma unroll
    for (int i = 0; i < 4; ++i) Bv[i] = *(const bf16x8*)(Bl + (size_t)(klo + i) * 512);

    floatx4 acc[4] = {};

    for (int kc0 = klo; kc0 <= khi; kc0 += 16) {
        #pragma unroll
        for (int s = 0; s < 16; ++s) {
            const int kc = kc0 + s;
            bf16x8 bcur = Bv[s & 3];
            acc[0] = MFMA(Q[(s + 0)  & 15], bcur, acc[0]);
            acc[1] = MFMA(Q[(s + 4)  & 15], bcur, acc[1]);
            acc[2] = MFMA(Q[(s + 8)  & 15], bcur, acc[2]);
            acc[3] = MFMA(Q[(s + 12) & 15], bcur, acc[3]);
            // slot s dead after r=0 use; refill from GLOBAL (vmem pipe)
            Q[s & 15] = *(const bf16x8*)(ga + 32 * (kc + 16));
            // B lookahead 4 iters; pad rows make kc+4 <= 131 safe, no wrap
            Bv[s & 3] = *(const bf16x8*)(Bl + (size_t)(kc + 4) * 512);
        }
    }

    // D layout: col = lane&15 (center), row-in-tile = quad*4 + e.
    // global lag row = 64wu + 16r + 4quad + e; phantom row 1023 excluded.
    float vmax = -INFINITY;
    #pragma unroll
    for (int r = 0; r < 4; ++r) {
        #pragma unroll
        for (int e = 0; e < 4; ++e) {
            bool phantom = (wu == 15) & (r == 3) & (quad == 3) & (e == 3);
            vmax = fmaxf(vmax, phantom ? -INFINITY : acc[r][e]);
        }
    }
    vmax = fmaxf(vmax, __shfl_xor(vmax, 16));
    vmax = fmaxf(vmax, __shfl_xor(vmax, 32));
    if (quad == 0) wred[wu][m] = vmax;
    __syncthreads();

    if (tid < 16) {
        float mm = wred[0][tid];
        #pragma unroll
        for (int i = 1; i < 16; ++i) mm = fmaxf(mm, wred[i][tid]);
        float denom = wsfn[b] * (float)tid;
        float d = (denom < 1e-9f) ? 0.f : mm / denom;
        dd[tid] = d;
        out[NB + b * NK + tid] = d;
    }
    __syncthreads();
    if (tid == 0) {
        float best = dd[0]; int lab = 0;
        #pragma unroll
        for (int k = 1; k < NK; ++k) if (dd[k] > best) { best = dd[k]; lab = k; }
        out[b] = (float)lab;
    }
}

extern "C" void kernel_launch(void* const* d_in, const int* in_sizes, int n_in,
                              void* d_out, int out_size, void* d_ws, size_t ws_size,
                              hipStream_t stream) {
    const float* x = (const float*)d_in[0];
    const float* c = (const float*)d_in[1];
    float* out  = (float*)d_out;
    float* wsfn = (float*)d_ws;                           // 256 floats
    __bf16* xpad = (__bf16*)((char*)d_ws + 4096);         // 256*1120*16 B = 4.59 MB

    prep_kernel<<<NB, 256, 0, stream>>>(x, xpad, wsfn);
    kshape_kernel<<<NB, 1024, 0, stream>>>(xpad, c, wsfn, out);
}

// Round 12
// 70.635 us; speedup vs baseline: 1.1130x; 1.1130x over previous
//
#include <hip/hip_runtime.h>
#include <math.h>

// KShape dists via i8 MFMA (K=64). B=256, K=16, SZ=512, D=8.
// corr[b,i,k] = sum_{t,d} xpad[b][(i+t)*8+d] * c[k][t*8+d],  i in [0,1022]
// dists[b,k] = max_i corr / (||x_b|| * k); k=0 -> 0. labels = first argmax.
// out: [0..255]=labels(float), [256..4351]=dists.
//
// R12: int8 path -- mfma_i32_16x16x64_i8 (K=64) halves iterations, LDS
// instructions and LDS bytes vs bf16 K=32. Symmetric quantization with true
// per-sample scale (x) and per-center scale (c); integer accumulate is
// exact, only quantization noise (predicted absmax ~0.04 < 0.0797).
// A-fragments: 16 consecutive bytes spanning 2 xpad rows; 16B alignment
// guaranteed via TWO parity-staggered LDS copies (even/odd row pairs);
// each lane's parity is constant -> one aligned ds_read_b128 per frag.
// Ring Q[8] (slack 2 iters), B FIFO-4, trapezoid windows at kc64 grain
// (klo=56-8wu, multiples of 8 -> unroll-8, compile-time ring indices).
// Single kernel, 256 blocks x 1024 threads (1/CU, 4 waves/SIMD, <=128 reg).

#define NB 256
#define NK 16
#define NS 512
#define ND 8

typedef int intx4 __attribute__((ext_vector_type(4)));

#define MFMA_I8(a, b, c) __builtin_amdgcn_mfma_i32_16x16x64_i8(a, b, c, 0, 0, 0)

__device__ __forceinline__ int q8(float v, float s) {
    return (int)rintf(fminf(fmaxf(v * s, -127.f), 127.f));
}
__device__ __forceinline__ unsigned pk4(int a, int b, int c, int d) {
    return (a & 255) | ((b & 255) << 8) | ((c & 255) << 16) | ((unsigned)(d & 255) << 24);
}

__global__ __launch_bounds__(1024, 4) void kshape_kernel(
    const float* __restrict__ x, const float* __restrict__ c, float* __restrict__ out)
{
    __shared__ __align__(16) char xqE[560 * 16];     // rows (2j, 2j+1)   8.75 KB
    __shared__ __align__(16) char xqO[560 * 16];     // rows (2j+1, 2j+2) 8.75 KB
    __shared__ __align__(16) char Bq[68 * 64 * 16];  // 68 KB (kc 0..67, 4-kc zero pad)
    __shared__ float Mc[16];
    __shared__ float redn[16], redm[16];
    __shared__ float s_Mb, s_nrm;
    __shared__ int   wredi[16][16];
    __shared__ float dd[16];

    const int tid = threadIdx.x;
    const int b   = blockIdx.x;
    const int L   = tid & 63;
    const int wu  = __builtin_amdgcn_readfirstlane(tid >> 6);  // wave 0..15

    // ---- zero xq copies + B pad ----
    {
        int4 z = {0, 0, 0, 0};
        if (tid < 560) { ((int4*)xqE)[tid] = z; ((int4*)xqO)[tid] = z; }
        if (tid < 256) ((int4*)(Bq + 64 * 64 * 16))[tid] = z;
    }

    // ---- pass 1: x stats (max|x|, sumsq) + per-center max|c| ----
    const float4* x4 = (const float4*)(x + (size_t)b * (NS * ND));  // 1024 float4
    float4 v = x4[tid];
    float am = fmaxf(fmaxf(fabsf(v.x), fabsf(v.y)), fmaxf(fabsf(v.z), fabsf(v.w)));
    float ss = v.x * v.x + v.y * v.y + v.z * v.z + v.w * v.w;
    const float4* cw = (const float4*)(c + (size_t)wu * (NS * ND)); // wave wu <-> center wu
    float cm = 0.f;
    #pragma unroll
    for (int i = 0; i < 16; ++i) {
        float4 w = cw[L + 64 * i];
        cm = fmaxf(cm, fmaxf(fmaxf(fabsf(w.x), fabsf(w.y)), fmaxf(fabsf(w.z), fabsf(w.w))));
    }
    #pragma unroll
    for (int off = 32; off; off >>= 1) {
        ss += __shfl_down(ss, off);
        am = fmaxf(am, __shfl_down(am, off));
        cm = fmaxf(cm, __shfl_down(cm, off));
    }
    if (L == 0) { redn[wu] = ss; redm[wu] = am; Mc[wu] = cm; }
    __syncthreads();

    // all threads compute Mb locally; thread0 stores norm/Mb for epilogue
    float Mb = redm[0];
    #pragma unroll
    for (int i = 1; i < 16; ++i) Mb = fmaxf(Mb, redm[i]);
    if (tid == 0) {
        float t = 0.f;
        #pragma unroll
        for (int i = 0; i < 16; ++i) t += redn[i];
        s_nrm = sqrtf(t);
        s_Mb  = Mb;
    }

    // ---- pass 2a: quantize x rows 511..1022 into both parity copies ----
    const float sx = (Mb > 0.f) ? 127.f / Mb : 0.f;
    if (tid < 512) {
        int row = 511 + tid;
        float4 a = x4[2 * tid], bb = x4[2 * tid + 1];
        unsigned lo = pk4(q8(a.x, sx), q8(a.y, sx), q8(a.z, sx), q8(a.w, sx));
        unsigned hi = pk4(q8(bb.x, sx), q8(bb.y, sx), q8(bb.z, sx), q8(bb.w, sx));
        uint2 pr = make_uint2(lo, hi);
        *(uint2*)(xqE + (row >> 1) * 16 + (row & 1) * 8) = pr;
        int lineO = (row & 1) ? (row >> 1) : (row >> 1) - 1;
        int offO  = (row & 1) ? 0 : 8;
        *(uint2*)(xqO + lineO * 16 + offO) = pr;
    }

    // ---- pass 2b: pack B fragments (kc 0..63) ----
    // frag f = kc*64 + Lf; Lf=(n,qd): elements j=0..15 = c[n][64kc+16qd+j]
    #pragma unroll
    for (int i = 0; i < 4; ++i) {
        int f = tid + 1024 * i;
        int kc = f >> 6, Lf = f & 63, n = Lf & 15, qd = Lf >> 4;
        int t0 = 8 * kc + 2 * qd;
        const float4* cn = (const float4*)(c + (size_t)n * (NS * ND));
        float4 a = cn[2 * t0], b2 = cn[2 * t0 + 1], c2 = cn[2 * t0 + 2], d2 = cn[2 * t0 + 3];
        float sc = (Mc[n] > 0.f) ? 127.f / Mc[n] : 0.f;
        int4 w;
        w.x = pk4(q8(a.x, sc), q8(a.y, sc), q8(a.z, sc), q8(a.w, sc));
        w.y = pk4(q8(b2.x, sc), q8(b2.y, sc), q8(b2.z, sc), q8(b2.w, sc));
        w.z = pk4(q8(c2.x, sc), q8(c2.y, sc), q8(c2.z, sc), q8(c2.w, sc));
        w.w = pk4(q8(d2.x, sc), q8(d2.y, sc), q8(d2.z, sc), q8(d2.w, sc));
        ((int4*)Bq)[f] = w;
    }
    __syncthreads();

    // ---- main loop ----
    const int m    = L & 15;       // A row within tile / D col (center id)
    const int quad = L >> 4;
    // wave-uniform kc64 window (multiples of 8)
    const int a0  = 56 - 8 * wu;
    const int klo = (a0 > 0) ? a0 : 0;                 // 56,48,...,8,0,...
    const int kh_ = 127 - 8 * wu;
    const int khi = (kh_ > 63) ? 63 : kh_;             // 63 x9, 55, ..., 7

    // lane parity p = m&1 (64wu even); line base in parity copy
    const char* base = ((m & 1) == 0) ? xqE : xqO;
    const char* ga   = base + ((((64 * wu + m) - (m & 1)) >> 1) + quad) * 16;
    // frag (r,kc) at ga + 64*(kc + 2r); ring slot (kc + 2r) & 7
    const char* Bl = Bq + L * 16;

    intx4 Q[8];
    #pragma unroll
    for (int i = 0; i < 8; ++i) Q[i] = *(const intx4*)(ga + 64 * (klo + i));
    intx4 Bv[4];
    #pragma unroll
    for (int i = 0; i < 4; ++i) Bv[i] = *(const intx4*)(Bl + (size_t)(klo + i) * 1024);

    intx4 acc[4] = {};

    for (int kc0 = klo; kc0 <= khi; kc0 += 8) {
        #pragma unroll
        for (int s = 0; s < 8; ++s) {
            const int kc = kc0 + s;
            intx4 bcur = Bv[s & 3];
            acc[0] = MFMA_I8(Q[(s + 0) & 7], bcur, acc[0]);
            acc[1] = MFMA_I8(Q[(s + 2) & 7], bcur, acc[1]);
            acc[2] = MFMA_I8(Q[(s + 4) & 7], bcur, acc[2]);
            acc[3] = MFMA_I8(Q[(s + 6) & 7], bcur, acc[3]);
            Q[s & 7]  = *(const intx4*)(ga + 64 * (kc + 8));         // line kc+8
            Bv[s & 3] = *(const intx4*)(Bl + (size_t)(kc + 4) * 1024); // pad-safe
        }
    }

    // ---- epilogue: int max over lags, scale, reduce, labels ----
    // D layout: col = lane&15 (center), row-in-tile = quad*4 + e.
    // global lag row = 64wu + 16r + 4quad + e; phantom row 1023 excluded.
    int vmax = (int)0x80000000;
    #pragma unroll
    for (int r = 0; r < 4; ++r) {
        #pragma unroll
        for (int e = 0; e < 4; ++e) {
            bool phantom = (wu == 15) & (r == 3) & (quad == 3) & (e == 3);
            int val = phantom ? (int)0x80000000 : acc[r][e];
            vmax = (val > vmax) ? val : vmax;
        }
    }
    { int o = __shfl_xor(vmax, 16); vmax = (o > vmax) ? o : vmax; }
    { int o = __shfl_xor(vmax, 32); vmax = (o > vmax) ? o : vmax; }
    if (quad == 0) wredi[wu][m] = vmax;
    __syncthreads();

    if (tid < 16) {
        int mm = wredi[0][tid];
        #pragma unroll
        for (int i = 1; i < 16; ++i) mm = (wredi[i][tid] > mm) ? wredi[i][tid] : mm;
        float scale = s_Mb * Mc[tid] * (1.0f / 16129.0f);   // (Mb/127)*(Mc/127)
        float denom = s_nrm * (float)tid;
        float d = (denom < 1e-9f) ? 0.f : ((float)mm * scale) / denom;
        dd[tid] = d;
        out[NB + b * NK + tid] = d;
    }
    __syncthreads();
    if (tid == 0) {
        float best = dd[0]; int lab = 0;
        #pragma unroll
        for (int k = 1; k < NK; ++k) if (dd[k] > best) { best = dd[k]; lab = k; }
        out[b] = (float)lab;
    }
}

extern "C" void kernel_launch(void* const* d_in, const int* in_sizes, int n_in,
                              void* d_out, int out_size, void* d_ws, size_t ws_size,
                              hipStream_t stream) {
    const float* x = (const float*)d_in[0];
    const float* c = (const float*)d_in[1];
    float* out = (float*)d_out;
    kshape_kernel<<<NB, 1024, 0, stream>>>(x, c, out);
}

// Round 13
// 65.638 us; speedup vs baseline: 1.1977x; 1.0761x over previous
//
#include <hip/hip_runtime.h>
#include <math.h>

// KShape dists via i8 MFMA (K=64). B=256, K=16, SZ=512, D=8.
// corr[b,i,k] = sum_{t,d} xpad[b][(i+t)*8+d] * c[k][t*8+d],  i in [0,1022]
// dists[b,k] = max_i corr / (||x_b|| * k); k=0 -> 0. labels = first argmax.
// out: [0..255]=labels(float), [256..4351]=dists.
//
// R13 = R12 (70.6us) with all per-block-redundant c-processing hoisted into
// a one-time pack kernel: Mc[n]=max|c[n]|, c quantized to i8 fragment layout
// in d_ws (68 KB incl. zeroed 4-kc pad -- d_ws is re-poisoned every call so
// the pad is re-zeroed each launch). Main kernel prologue: 68 KB int4 L2->LDS
// copy + x stats + x quantize only. Loop/epilogue identical to R12.

#define NB 256
#define NK 16
#define NS 512
#define ND 8

typedef int intx4 __attribute__((ext_vector_type(4)));

#define MFMA_I8(a, b, c) __builtin_amdgcn_mfma_i32_16x16x64_i8(a, b, c, 0, 0, 0)

__device__ __forceinline__ int q8(float v, float s) {
    return (int)rintf(fminf(fmaxf(v * s, -127.f), 127.f));
}
__device__ __forceinline__ unsigned pk4(int a, int b, int c, int d) {
    return (a & 255) | ((b & 255) << 8) | ((c & 255) << 16) | ((unsigned)(d & 255) << 24);
}

// ---- pack: per-center max + quantize c into i8 fragment layout ----
// Bq frag (kc, L): 16 bytes = c[n = L&15][64kc + 16*(L>>4) + j], j=0..15, scaled 127/Mc[n].
__global__ __launch_bounds__(256) void pack_kernel(
    const float* __restrict__ c, char* __restrict__ Bq, float* __restrict__ Mc)
{
    const int tid = threadIdx.x;
    const int blk = blockIdx.x;
    if (blk == 16) {                 // zero the 4-kc lookahead pad (kc 64..67)
        int4 z = {0, 0, 0, 0};
        ((int4*)(Bq + 64 * 1024))[tid] = z;
        return;
    }
    __shared__ float red[4];
    const int n = blk;
    const float4* cn = (const float4*)(c + (size_t)n * (NS * ND));   // 1024 float4
    float cm = 0.f;
    #pragma unroll
    for (int i = 0; i < 4; ++i) {
        float4 v = cn[tid + 256 * i];
        cm = fmaxf(cm, fmaxf(fmaxf(fabsf(v.x), fabsf(v.y)), fmaxf(fabsf(v.z), fabsf(v.w))));
    }
    #pragma unroll
    for (int off = 32; off; off >>= 1) cm = fmaxf(cm, __shfl_down(cm, off));
    if ((tid & 63) == 0) red[tid >> 6] = cm;
    __syncthreads();
    const float M = fmaxf(fmaxf(red[0], red[1]), fmaxf(red[2], red[3]));
    if (tid == 0) Mc[n] = M;
    const float sc = (M > 0.f) ? 127.f / M : 0.f;
    // thread t -> (kc = t>>2, qd = t&3): elements c[n][64kc+16qd+0..15]
    const int kc = tid >> 2, qd = tid & 3;
    const int f4 = 16 * kc + 4 * qd;
    float4 a = cn[f4], b2 = cn[f4 + 1], c2 = cn[f4 + 2], d2 = cn[f4 + 3];
    int4 w;
    w.x = pk4(q8(a.x, sc),  q8(a.y, sc),  q8(a.z, sc),  q8(a.w, sc));
    w.y = pk4(q8(b2.x, sc), q8(b2.y, sc), q8(b2.z, sc), q8(b2.w, sc));
    w.z = pk4(q8(c2.x, sc), q8(c2.y, sc), q8(c2.z, sc), q8(c2.w, sc));
    w.w = pk4(q8(d2.x, sc), q8(d2.y, sc), q8(d2.z, sc), q8(d2.w, sc));
    *(int4*)(Bq + (size_t)kc * 1024 + (size_t)(qd * 16 + n) * 16) = w;
}

// ---- main: one block = one b; 16 waves x 4 row-tiles = 1024 lag rows ----
__global__ __launch_bounds__(1024, 4) void kshape_kernel(
    const float* __restrict__ x, const char* __restrict__ Bqg,
    const float* __restrict__ Mc, float* __restrict__ out)
{
    __shared__ __align__(16) char xqE[560 * 16];     // rows (2j, 2j+1)   8.75 KB
    __shared__ __align__(16) char xqO[560 * 16];     // rows (2j+1, 2j+2) 8.75 KB
    __shared__ __align__(16) char Bq[68 * 64 * 16];  // 68 KB packed B + pad
    __shared__ float sMc[16];
    __shared__ float redn[16], redm[16];
    __shared__ int   wredi[16][16];
    __shared__ float dd[16];

    const int tid = threadIdx.x;
    const int b   = blockIdx.x;
    const int L   = tid & 63;
    const int wu  = __builtin_amdgcn_readfirstlane(tid >> 6);  // wave 0..15

    // ---- phase 0: zero xq copies, copy packed B into LDS, load Mc ----
    {
        int4 z = {0, 0, 0, 0};
        if (tid < 560) { ((int4*)xqE)[tid] = z; ((int4*)xqO)[tid] = z; }
    }
    #pragma unroll
    for (int i = 0; i < 5; ++i) {
        int idx = tid + 1024 * i;
        if (idx < 4352) ((int4*)Bq)[idx] = ((const int4*)Bqg)[idx];
    }
    if (tid < 16) sMc[tid] = Mc[tid];

    // ---- x stats: max|x|, sumsq ----
    const float4* x4 = (const float4*)(x + (size_t)b * (NS * ND));  // 1024 float4
    {
        float4 v = x4[tid];
        float am = fmaxf(fmaxf(fabsf(v.x), fabsf(v.y)), fmaxf(fabsf(v.z), fabsf(v.w)));
        float ss = v.x * v.x + v.y * v.y + v.z * v.z + v.w * v.w;
        #pragma unroll
        for (int off = 32; off; off >>= 1) {
            ss += __shfl_down(ss, off);
            am = fmaxf(am, __shfl_down(am, off));
        }
        if (L == 0) { redn[wu] = ss; redm[wu] = am; }
    }
    __syncthreads();

    // ---- quantize x rows 511..1022 into both parity copies ----
    if (tid < 512) {
        float Mb = redm[0];
        #pragma unroll
        for (int i = 1; i < 16; ++i) Mb = fmaxf(Mb, redm[i]);
        const float sx = (Mb > 0.f) ? 127.f / Mb : 0.f;
        int row = 511 + tid;
        float4 a = x4[2 * tid], bb = x4[2 * tid + 1];
        unsigned lo = pk4(q8(a.x, sx), q8(a.y, sx), q8(a.z, sx), q8(a.w, sx));
        unsigned hi = pk4(q8(bb.x, sx), q8(bb.y, sx), q8(bb.z, sx), q8(bb.w, sx));
        uint2 pr = make_uint2(lo, hi);
        *(uint2*)(xqE + (row >> 1) * 16 + (row & 1) * 8) = pr;
        int lineO = (row & 1) ? (row >> 1) : (row >> 1) - 1;
        int offO  = (row & 1) ? 0 : 8;
        *(uint2*)(xqO + lineO * 16 + offO) = pr;
    }
    __syncthreads();

    // ---- main loop (identical to R12) ----
    const int m    = L & 15;       // A row within tile / D col (center id)
    const int quad = L >> 4;
    const int a0  = 56 - 8 * wu;
    const int klo = (a0 > 0) ? a0 : 0;                 // 56,48,...,8,0,...
    const int kh_ = 127 - 8 * wu;
    const int khi = (kh_ > 63) ? 63 : kh_;             // 63 x9, 55, ..., 7

    const char* base = ((m & 1) == 0) ? xqE : xqO;
    const char* ga   = base + ((((64 * wu + m) - (m & 1)) >> 1) + quad) * 16;
    const char* Bl = Bq + L * 16;

    intx4 Q[8];
    #pragma unroll
    for (int i = 0; i < 8; ++i) Q[i] = *(const intx4*)(ga + 64 * (klo + i));
    intx4 Bv[4];
    #pragma unroll
    for (int i = 0; i < 4; ++i) Bv[i] = *(const intx4*)(Bl + (size_t)(klo + i) * 1024);

    intx4 acc[4] = {};

    for (int kc0 = klo; kc0 <= khi; kc0 += 8) {
        #pragma unroll
        for (int s = 0; s < 8; ++s) {
            const int kc = kc0 + s;
            intx4 bcur = Bv[s & 3];
            acc[0] = MFMA_I8(Q[(s + 0) & 7], bcur, acc[0]);
            acc[1] = MFMA_I8(Q[(s + 2) & 7], bcur, acc[1]);
            acc[2] = MFMA_I8(Q[(s + 4) & 7], bcur, acc[2]);
            acc[3] = MFMA_I8(Q[(s + 6) & 7], bcur, acc[3]);
            Q[s & 7]  = *(const intx4*)(ga + 64 * (kc + 8));
            Bv[s & 3] = *(const intx4*)(Bl + (size_t)(kc + 4) * 1024);
        }
    }

    // ---- epilogue ----
    // D layout: col = lane&15 (center), row-in-tile = quad*4 + e.
    // global lag row = 64wu + 16r + 4quad + e; phantom row 1023 excluded.
    int vmax = (int)0x80000000;
    #pragma unroll
    for (int r = 0; r < 4; ++r) {
        #pragma unroll
        for (int e = 0; e < 4; ++e) {
            bool phantom = (wu == 15) & (r == 3) & (quad == 3) & (e == 3);
            int val = phantom ? (int)0x80000000 : acc[r][e];
            vmax = (val > vmax) ? val : vmax;
        }
    }
    { int o = __shfl_xor(vmax, 16); vmax = (o > vmax) ? o : vmax; }
    { int o = __shfl_xor(vmax, 32); vmax = (o > vmax) ? o : vmax; }
    if (quad == 0) wredi[wu][m] = vmax;
    __syncthreads();

    if (tid < 16) {
        int mm = wredi[0][tid];
        #pragma unroll
        for (int i = 1; i < 16; ++i) mm = (wredi[i][tid] > mm) ? wredi[i][tid] : mm;
        float Mb = redm[0];
        float t = 0.f;
        #pragma unroll
        for (int i = 0; i < 16; ++i) { Mb = fmaxf(Mb, redm[i]); t += redn[i]; }
        float nrm = sqrtf(t);
        float scale = Mb * sMc[tid] * (1.0f / 16129.0f);   // (Mb/127)*(Mc/127)
        float denom = nrm * (float)tid;
        float d = (denom < 1e-9f) ? 0.f : ((float)mm * scale) / denom;
        dd[tid] = d;
        out[NB + b * NK + tid] = d;
    }
    __syncthreads();
    if (tid == 0) {
        float best = dd[0]; int lab = 0;
        #pragma unroll
        for (int k = 1; k < NK; ++k) if (dd[k] > best) { best = dd[k]; lab = k; }
        out[b] = (float)lab;
    }
}

extern "C" void kernel_launch(void* const* d_in, const int* in_sizes, int n_in,
                              void* d_out, int out_size, void* d_ws, size_t ws_size,
                              hipStream_t stream) {
    const float* x = (const float*)d_in[0];
    const float* c = (const float*)d_in[1];
    float* out = (float*)d_out;
    char*  Bq  = (char*)d_ws;                          // 68 KB packed i8 B
    float* Mc  = (float*)((char*)d_ws + 70656);        // 16 floats

    pack_kernel<<<17, 256, 0, stream>>>(c, Bq, Mc);
    kshape_kernel<<<NB, 1024, 0, stream>>>(x, Bq, Mc, out);
}

// Round 14
// 65.276 us; speedup vs baseline: 1.2043x; 1.0055x over previous
//
#include <hip/hip_runtime.h>
#include <math.h>

// KShape dists via i8 MFMA (K=64). B=256, K=16, SZ=512, D=8.
// corr[b,i,k] = sum_{t,d} xpad[b][(i+t)*8+d] * c[k][t*8+d],  i in [0,1022]
// dists[b,k] = max_i corr / (||x_b|| * k); k=0 -> 0. labels = first argmax.
// out: [0..255]=labels(float), [256..4351]=dists.
//
// R14 = R13 (65.6us) + B-FIFO depth 8 (lookahead ~190cy > ~120cy LDS
// latency; depth 4 was ~95cy -> per-iter stall). Pad extended to 8 kc
// (Bq = 72 KB); pack kernel zeroes the pad each call (d_ws re-poisoned).
// Arithmetic identical to R12/R13 -> absmax 0.03125.

#define NB 256
#define NK 16
#define NS 512
#define ND 8

typedef int intx4 __attribute__((ext_vector_type(4)));

#define MFMA_I8(a, b, c) __builtin_amdgcn_mfma_i32_16x16x64_i8(a, b, c, 0, 0, 0)

__device__ __forceinline__ int q8(float v, float s) {
    return (int)rintf(fminf(fmaxf(v * s, -127.f), 127.f));
}
__device__ __forceinline__ unsigned pk4(int a, int b, int c, int d) {
    return (a & 255) | ((b & 255) << 8) | ((c & 255) << 16) | ((unsigned)(d & 255) << 24);
}

// ---- pack: per-center max + quantize c into i8 fragment layout ----
// Bq frag (kc, L): 16 bytes = c[n = L&15][64kc + 16*(L>>4) + j], j=0..15, scaled 127/Mc[n].
__global__ __launch_bounds__(256) void pack_kernel(
    const float* __restrict__ c, char* __restrict__ Bq, float* __restrict__ Mc)
{
    const int tid = threadIdx.x;
    const int blk = blockIdx.x;
    if (blk == 16) {                 // zero the 8-kc lookahead pad (kc 64..71)
        int4 z = {0, 0, 0, 0};
        ((int4*)(Bq + 64 * 1024))[tid] = z;
        ((int4*)(Bq + 64 * 1024))[tid + 256] = z;
        return;
    }
    __shared__ float red[4];
    const int n = blk;
    const float4* cn = (const float4*)(c + (size_t)n * (NS * ND));   // 1024 float4
    float cm = 0.f;
    #pragma unroll
    for (int i = 0; i < 4; ++i) {
        float4 v = cn[tid + 256 * i];
        cm = fmaxf(cm, fmaxf(fmaxf(fabsf(v.x), fabsf(v.y)), fmaxf(fabsf(v.z), fabsf(v.w))));
    }
    #pragma unroll
    for (int off = 32; off; off >>= 1) cm = fmaxf(cm, __shfl_down(cm, off));
    if ((tid & 63) == 0) red[tid >> 6] = cm;
    __syncthreads();
    const float M = fmaxf(fmaxf(red[0], red[1]), fmaxf(red[2], red[3]));
    if (tid == 0) Mc[n] = M;
    const float sc = (M > 0.f) ? 127.f / M : 0.f;
    // thread t -> (kc = t>>2, qd = t&3): elements c[n][64kc+16qd+0..15]
    const int kc = tid >> 2, qd = tid & 3;
    const int f4 = 16 * kc + 4 * qd;
    float4 a = cn[f4], b2 = cn[f4 + 1], c2 = cn[f4 + 2], d2 = cn[f4 + 3];
    int4 w;
    w.x = pk4(q8(a.x, sc),  q8(a.y, sc),  q8(a.z, sc),  q8(a.w, sc));
    w.y = pk4(q8(b2.x, sc), q8(b2.y, sc), q8(b2.z, sc), q8(b2.w, sc));
    w.z = pk4(q8(c2.x, sc), q8(c2.y, sc), q8(c2.z, sc), q8(c2.w, sc));
    w.w = pk4(q8(d2.x, sc), q8(d2.y, sc), q8(d2.z, sc), q8(d2.w, sc));
    *(int4*)(Bq + (size_t)kc * 1024 + (size_t)(qd * 16 + n) * 16) = w;
}

// ---- main: one block = one b; 16 waves x 4 row-tiles = 1024 lag rows ----
__global__ __launch_bounds__(1024, 4) void kshape_kernel(
    const float* __restrict__ x, const char* __restrict__ Bqg,
    const float* __restrict__ Mc, float* __restrict__ out)
{
    __shared__ __align__(16) char xqE[560 * 16];     // rows (2j, 2j+1)   8.75 KB
    __shared__ __align__(16) char xqO[560 * 16];     // rows (2j+1, 2j+2) 8.75 KB
    __shared__ __align__(16) char Bq[72 * 64 * 16];  // 72 KB packed B + 8-kc pad
    __shared__ float sMc[16];
    __shared__ float redn[16], redm[16];
    __shared__ int   wredi[16][16];
    __shared__ float dd[16];

    const int tid = threadIdx.x;
    const int b   = blockIdx.x;
    const int L   = tid & 63;
    const int wu  = __builtin_amdgcn_readfirstlane(tid >> 6);  // wave 0..15

    // ---- phase 0: zero xq copies, copy packed B (incl. pad) into LDS ----
    {
        int4 z = {0, 0, 0, 0};
        if (tid < 560) { ((int4*)xqE)[tid] = z; ((int4*)xqO)[tid] = z; }
    }
    #pragma unroll
    for (int i = 0; i < 4; ++i)
        ((int4*)Bq)[tid + 1024 * i] = ((const int4*)Bqg)[tid + 1024 * i];
    if (tid < 512) ((int4*)Bq)[tid + 4096] = ((const int4*)Bqg)[tid + 4096];
    if (tid < 16) sMc[tid] = Mc[tid];

    // ---- x stats: max|x|, sumsq ----
    const float4* x4 = (const float4*)(x + (size_t)b * (NS * ND));  // 1024 float4
    {
        float4 v = x4[tid];
        float am = fmaxf(fmaxf(fabsf(v.x), fabsf(v.y)), fmaxf(fabsf(v.z), fabsf(v.w)));
        float ss = v.x * v.x + v.y * v.y + v.z * v.z + v.w * v.w;
        #pragma unroll
        for (int off = 32; off; off >>= 1) {
            ss += __shfl_down(ss, off);
            am = fmaxf(am, __shfl_down(am, off));
        }
        if (L == 0) { redn[wu] = ss; redm[wu] = am; }
    }
    __syncthreads();

    // ---- quantize x rows 511..1022 into both parity copies ----
    if (tid < 512) {
        float Mb = redm[0];
        #pragma unroll
        for (int i = 1; i < 16; ++i) Mb = fmaxf(Mb, redm[i]);
        const float sx = (Mb > 0.f) ? 127.f / Mb : 0.f;
        int row = 511 + tid;
        float4 a = x4[2 * tid], bb = x4[2 * tid + 1];
        unsigned lo = pk4(q8(a.x, sx), q8(a.y, sx), q8(a.z, sx), q8(a.w, sx));
        unsigned hi = pk4(q8(bb.x, sx), q8(bb.y, sx), q8(bb.z, sx), q8(bb.w, sx));
        uint2 pr = make_uint2(lo, hi);
        *(uint2*)(xqE + (row >> 1) * 16 + (row & 1) * 8) = pr;
        int lineO = (row & 1) ? (row >> 1) : (row >> 1) - 1;
        int offO  = (row & 1) ? 0 : 8;
        *(uint2*)(xqO + lineO * 16 + offO) = pr;
    }
    __syncthreads();

    // ---- main loop ----
    const int m    = L & 15;       // A row within tile / D col (center id)
    const int quad = L >> 4;
    const int a0  = 56 - 8 * wu;
    const int klo = (a0 > 0) ? a0 : 0;                 // 56,48,...,8,0,...
    const int kh_ = 127 - 8 * wu;
    const int khi = (kh_ > 63) ? 63 : kh_;             // 63 x9, 55, ..., 7

    const char* base = ((m & 1) == 0) ? xqE : xqO;
    const char* ga   = base + ((((64 * wu + m) - (m & 1)) >> 1) + quad) * 16;
    const char* Bl = Bq + L * 16;

    intx4 Q[8];
    #pragma unroll
    for (int i = 0; i < 8; ++i) Q[i] = *(const intx4*)(ga + 64 * (klo + i));
    intx4 Bv[8];
    #pragma unroll
    for (int i = 0; i < 8; ++i) Bv[i] = *(const intx4*)(Bl + (size_t)(klo + i) * 1024);

    intx4 acc[4] = {};

    for (int kc0 = klo; kc0 <= khi; kc0 += 8) {
        #pragma unroll
        for (int s = 0; s < 8; ++s) {
            const int kc = kc0 + s;
            intx4 bcur = Bv[s];
            acc[0] = MFMA_I8(Q[(s + 0) & 7], bcur, acc[0]);
            acc[1] = MFMA_I8(Q[(s + 2) & 7], bcur, acc[1]);
            acc[2] = MFMA_I8(Q[(s + 4) & 7], bcur, acc[2]);
            acc[3] = MFMA_I8(Q[(s + 6) & 7], bcur, acc[3]);
            Q[s & 7] = *(const intx4*)(ga + 64 * (kc + 8));
            Bv[s]    = *(const intx4*)(Bl + (size_t)(kc + 8) * 1024);   // pad-safe to kc71
        }
    }

    // ---- epilogue ----
    // D layout: col = lane&15 (center), row-in-tile = quad*4 + e.
    // global lag row = 64wu + 16r + 4quad + e; phantom row 1023 excluded.
    int vmax = (int)0x80000000;
    #pragma unroll
    for (int r = 0; r < 4; ++r) {
        #pragma unroll
        for (int e = 0; e < 4; ++e) {
            bool phantom = (wu == 15) & (r == 3) & (quad == 3) & (e == 3);
            int val = phantom ? (int)0x80000000 : acc[r][e];
            vmax = (val > vmax) ? val : vmax;
        }
    }
    { int o = __shfl_xor(vmax, 16); vmax = (o > vmax) ? o : vmax; }
    { int o = __shfl_xor(vmax, 32); vmax = (o > vmax) ? o : vmax; }
    if (quad == 0) wredi[wu][m] = vmax;
    __syncthreads();

    if (tid < 16) {
        int mm = wredi[0][tid];
        #pragma unroll
        for (int i = 1; i < 16; ++i) mm = (wredi[i][tid] > mm) ? wredi[i][tid] : mm;
        float Mb = redm[0];
        float t = 0.f;
        #pragma unroll
        for (int i = 0; i < 16; ++i) { Mb = fmaxf(Mb, redm[i]); t += redn[i]; }
        float nrm = sqrtf(t);
        float scale = Mb * sMc[tid] * (1.0f / 16129.0f);   // (Mb/127)*(Mc/127)
        float denom = nrm * (float)tid;
        float d = (denom < 1e-9f) ? 0.f : ((float)mm * scale) / denom;
        dd[tid] = d;
        out[NB + b * NK + tid] = d;
    }
    __syncthreads();
    if (tid == 0) {
        float best = dd[0]; int lab = 0;
        #pragma unroll
        for (int k = 1; k < NK; ++k) if (dd[k] > best) { best = dd[k]; lab = k; }
        out[b] = (float)lab;
    }
}

extern "C" void kernel_launch(void* const* d_in, const int* in_sizes, int n_in,
                              void* d_out, int out_size, void* d_ws, size_t ws_size,
                              hipStream_t stream) {
    const float* x = (const float*)d_in[0];
    const float* c = (const float*)d_in[1];
    float* out = (float*)d_out;
    char*  Bq  = (char*)d_ws;                          // 72 KB packed i8 B (incl. pad)
    float* Mc  = (float*)((char*)d_ws + 73728);        // 16 floats

    pack_kernel<<<17, 256, 0, stream>>>(c, Bq, Mc);
    kshape_kernel<<<NB, 1024, 0, stream>>>(x, Bq, Mc, out);
}